// Round 15
// baseline (71.770 us; speedup 1.0000x reference)
//
#include <hip/hip_runtime.h>
#include <hip/hip_bf16.h>

// MSTGCN head — fused bf16-MFMA implementation (round 15).
// cheb = [I,-I,I] (identity adjacency) => graph conv = per-(b,n) GEMM with
// te = theta0 - theta1 + theta2.
//
// Round-15 vs rounds 8-14 (plateau 49-54µs across all lockstep-block configs):
// FULLY INDEPENDENT 1-WAVE BLOCKS. 64-thread blocks, grid 4096, zero barriers,
// zero shared weight buffer. Each wave: 4 pairs, own 6KB LDS tile, weight
// B-fragments loaded straight from global (120KB, L2-resident, unrolled ->
// high MLP). __launch_bounds__(64,4) caps at 128 VGPR -> 4 independent
// waves/SIMD (16/CU), each at a different chain position -> stalls hide under
// neighbors. Single-acc two-pass GEMMs (48 acc) + aC X-cache (48) + misc ~25
// = ~121 regs, fits. DPP LN kept. R7's version of this pattern failed at 84
// regs with 12 LOCKSTEP waves; this is the independence retest at 128 regs.

typedef __attribute__((ext_vector_type(8))) short bf16x8;
typedef __attribute__((ext_vector_type(4))) float f32x4;

#define FR_W1   0     // 32 frags: ks(4)*8 + {nt | 4+nt}   [te0|rw0T]
#define FR_TW0  32    // 24 frags: dt*8 + ks(2)*4 + nt(4)
#define FR_W2   56    // 16 frags: ks(2)*8 + {nt | 4+nt}   [te1|rw1T]
#define FR_TW1  72    // 24 frags
#define FR_FW   96    // 24 frags: ks(24), N=16 (cols 12..15 zero)
#define N_FRAGS 120

__device__ __forceinline__ unsigned short f2bf(float f) {
    unsigned u = __builtin_bit_cast(unsigned, f);
    return (unsigned short)((u + 0x7FFFu + ((u >> 16) & 1u)) >> 16);
}

__device__ __forceinline__ unsigned short hcvt(float f) {
    union { __hip_bfloat16 h; unsigned short u; } cv;
    cv.h = __float2bfloat16(f);
    return cv.u;
}

// 16-lane (DPP row) all-reduce add, pure VALU.
template <int CTRL>
__device__ __forceinline__ float dpp_add(float v) {
    int t = __builtin_amdgcn_update_dpp(0, __builtin_bit_cast(int, v),
                                        CTRL, 0xf, 0xf, true);
    return v + __builtin_bit_cast(float, t);
}
__device__ __forceinline__ float red16(float v) {
    v = dpp_add<0xB1>(v);    // quad_perm xor1
    v = dpp_add<0x4E>(v);    // quad_perm xor2
    v = dpp_add<0x141>(v);   // row_half_mirror (xor4 effective)
    v = dpp_add<0x140>(v);   // row_mirror      (xor8 effective)
    return v;
}

__global__ void prep(const float* __restrict__ th0, const float* __restrict__ tw0,
                     const float* __restrict__ rw0, const float* __restrict__ th1,
                     const float* __restrict__ tw1, const float* __restrict__ rw1,
                     const float* __restrict__ fw,  short* __restrict__ wsb)
{
    int e = blockIdx.x * 256 + threadIdx.x;     // (frag, lane, i)
    if (e >= N_FRAGS * 512) return;
    int frag = e >> 9;
    int l    = (e >> 3) & 63;
    int i    = e & 7;
    int kif  = ((l >> 4) << 3) + i;             // k within 32-chunk
    int nif  = l & 15;
    float val = 0.f;
    if (frag < 32) {                                       // W1
        int ks = frag >> 3, nt = frag & 7;
        int k = ks * 32 + kif, n = nt * 16 + nif;
        if (n < 64) val = th0[k*64+n] - th0[8192 + k*64+n] + th0[16384 + k*64+n];
        else        val = rw0[(n - 64) * 128 + k];
    } else if (frag < 56) {                                // TW0
        int q = frag - 32; int dt = q >> 3, ks = (q >> 2) & 1, nt = q & 3;
        int c = ks * 32 + kif, o = nt * 16 + nif;
        val = tw0[o * 192 + c * 3 + dt];
    } else if (frag < 72) {                                // W2
        int q = frag - 56; int ks = q >> 3, nt = q & 7;
        int k = ks * 32 + kif, n = nt * 16 + nif;
        if (n < 64) val = th1[k*64+n] - th1[4096 + k*64+n] + th1[8192 + k*64+n];
        else        val = rw1[(n - 64) * 64 + k];
    } else if (frag < 96) {                                // TW1
        int q = frag - 72; int dt = q >> 3, ks = (q >> 2) & 1, nt = q & 3;
        int c = ks * 32 + kif, o = nt * 16 + nif;
        val = tw1[o * 192 + c * 3 + dt];
    } else {                                               // FW
        int ks = frag - 96; int k = ks * 32 + kif; int po = nif;
        val = (po < 12) ? fw[po * 768 + k] : 0.f;
    }
    wsb[e] = (short)f2bf(val);
}

__global__ __launch_bounds__(64, 4) void mstgcn_mfma(
    const float* __restrict__ x,   const short* __restrict__ wsb,
    const float* __restrict__ tb0, const float* __restrict__ rb0,
    const float* __restrict__ lg0, const float* __restrict__ lb0,
    const float* __restrict__ tb1, const float* __restrict__ rb1,
    const float* __restrict__ lg1, const float* __restrict__ lb1,
    const float* __restrict__ fb,  float* __restrict__ out)
{
    __shared__ __align__(16) char LDS[6144];   // this wave's 48x64 bf16 tile

    const int lane = threadIdx.x;               // 0..63 (1 wave per block)
    const int l15  = lane & 15;
    const int l4   = lane >> 4;
    const int pair0 = blockIdx.x * 4;

    char* syB = LDS;

    auto gld = [&](int fg) -> bf16x8 {          // weight frag from global (L2)
        return *(const bf16x8*)(wsb + fg * 512 + lane * 8);
    };

    // A-row decode (rows 0..47; row -> (pair, t))
    int tA[3];
    long gbase[3];
    #pragma unroll
    for (int mt = 0; mt < 3; ++mt) {
        int r = mt * 16 + l15;
        int p = r / 12;
        tA[mt]   = r - p * 12;
        gbase[mt] = ((long)(pair0 + p) * 12 + tA[mt]) * 128;
    }

    f32x4 acc[3][4];
    bf16x8 aC[12];       // X A-fragment cache [ks*3+mt]

    // ============ GEMM1 pass S: X @ te0, building A-cache ============
    #pragma unroll
    for (int mt = 0; mt < 3; ++mt)
        #pragma unroll
        for (int nt = 0; nt < 4; ++nt) acc[mt][nt] = (f32x4)0.f;
    #pragma unroll
    for (int ks = 0; ks < 4; ++ks) {
        #pragma unroll
        for (int mt = 0; mt < 3; ++mt) {
            const float* pp = x + gbase[mt] + ks * 32 + l4 * 8;
            float v[8];
            *(float4*)(v)     = *(const float4*)(pp);
            *(float4*)(v + 4) = *(const float4*)(pp + 4);
            bf16x8 af;
            #pragma unroll
            for (int j = 0; j < 8; ++j) af[j] = (short)hcvt(v[j]);
            aC[ks * 3 + mt] = af;
        }
        #pragma unroll
        for (int nt = 0; nt < 4; ++nt) {
            bf16x8 b = gld(FR_W1 + ks * 8 + nt);
            #pragma unroll
            for (int mt = 0; mt < 3; ++mt)
                acc[mt][nt] = __builtin_amdgcn_mfma_f32_16x16x32_bf16(aC[ks * 3 + mt], b, acc[mt][nt], 0, 0, 0);
        }
    }
    // s = relu(acc) -> tile (swizzled bf16); wave-private, no barrier
    #pragma unroll
    for (int mt = 0; mt < 3; ++mt)
        #pragma unroll
        for (int j = 0; j < 4; ++j) {
            int row = mt * 16 + l4 * 4 + j;
            int sw  = (row & 7) << 4;
            #pragma unroll
            for (int nt = 0; nt < 4; ++nt) {
                int col = nt * 16 + l15;
                *(short*)(syB + row * 128 + ((col * 2) ^ sw)) =
                    (short)hcvt(fmaxf(acc[mt][nt][j], 0.f));
            }
        }

    // ============ GEMM1 pass R: cached A @ rw0T ============
    #pragma unroll
    for (int mt = 0; mt < 3; ++mt)
        #pragma unroll
        for (int nt = 0; nt < 4; ++nt) acc[mt][nt] = (f32x4)0.f;
    #pragma unroll
    for (int ks = 0; ks < 4; ++ks)
        #pragma unroll
        for (int nt = 0; nt < 4; ++nt) {
            bf16x8 b = gld(FR_W1 + ks * 8 + 4 + nt);
            #pragma unroll
            for (int mt = 0; mt < 3; ++mt)
                acc[mt][nt] = __builtin_amdgcn_mfma_f32_16x16x32_bf16(aC[ks * 3 + mt], b, acc[mt][nt], 0, 0, 0);
        }

    // ============ tconv0 (3 shifted GEMMs) += acc ============
    #pragma unroll
    for (int dt = 0; dt < 3; ++dt) {
        #pragma unroll
        for (int ks = 0; ks < 2; ++ks) {
            bf16x8 a[3];
            #pragma unroll
            for (int mt = 0; mt < 3; ++mt) {
                int ts    = tA[mt] + dt - 1;
                bool ok   = (ts >= 0) && (ts < 12);
                int srow  = ok ? (mt * 16 + l15 + dt - 1) : (mt * 16 + l15);
                int kb    = (ks * 32 + l4 * 8) * 2;
                bf16x8 av = *(const bf16x8*)(syB + srow * 128 + (kb ^ ((srow & 7) << 4)));
                a[mt] = ok ? av : (bf16x8)(short)0;
            }
            #pragma unroll
            for (int nt = 0; nt < 4; ++nt) {
                bf16x8 b = gld(FR_TW0 + dt * 8 + ks * 4 + nt);
                #pragma unroll
                for (int mt = 0; mt < 3; ++mt)
                    acc[mt][nt] = __builtin_amdgcn_mfma_f32_16x16x32_bf16(a[mt], b, acc[mt][nt], 0, 0, 0);
            }
        }
    }

    // ============ bias + relu + LN0 -> y1 into tile (DPP) ============
    {
        float bv[4], lgv[4], lbv[4];
        #pragma unroll
        for (int nt = 0; nt < 4; ++nt) {
            int col = nt * 16 + l15;
            bv[nt]  = rb0[col] + tb0[col];
            lgv[nt] = lg0[col];
            lbv[nt] = lb0[col];
        }
        #pragma unroll
        for (int mt = 0; mt < 3; ++mt)
            #pragma unroll
            for (int j = 0; j < 4; ++j) {
                float v[4], sm = 0.f, sq = 0.f;
                #pragma unroll
                for (int nt = 0; nt < 4; ++nt) {
                    v[nt] = fmaxf(acc[mt][nt][j] + bv[nt], 0.f);
                    sm += v[nt]; sq += v[nt] * v[nt];
                }
                sm = red16(sm);
                sq = red16(sq);
                float mu = sm * 0.015625f;
                float is = rsqrtf(sq * 0.015625f - mu * mu + 1e-5f);
                int row = mt * 16 + l4 * 4 + j;
                int sw  = (row & 7) << 4;
                #pragma unroll
                for (int nt = 0; nt < 4; ++nt) {
                    int col = nt * 16 + l15;
                    *(short*)(syB + row * 128 + ((col * 2) ^ sw)) =
                        (short)hcvt((v[nt] - mu) * is * lgv[nt] + lbv[nt]);
                }
            }
    }

    // cache y1 A-frags (same-wave RAW on LDS is issue-ordered, safe)
    bf16x8 aC2[6];
    #pragma unroll
    for (int ks = 0; ks < 2; ++ks)
        #pragma unroll
        for (int mt = 0; mt < 3; ++mt) {
            int row = mt * 16 + l15;
            int kb  = (ks * 32 + l4 * 8) * 2;
            aC2[ks * 3 + mt] = *(const bf16x8*)(syB + row * 128 + (kb ^ ((row & 7) << 4)));
        }

    // ============ GEMM2 pass S2: y1 @ te1 ============
    #pragma unroll
    for (int mt = 0; mt < 3; ++mt)
        #pragma unroll
        for (int nt = 0; nt < 4; ++nt) acc[mt][nt] = (f32x4)0.f;
    #pragma unroll
    for (int ks = 0; ks < 2; ++ks)
        #pragma unroll
        for (int nt = 0; nt < 4; ++nt) {
            bf16x8 b = gld(FR_W2 + ks * 8 + nt);
            #pragma unroll
            for (int mt = 0; mt < 3; ++mt)
                acc[mt][nt] = __builtin_amdgcn_mfma_f32_16x16x32_bf16(aC2[ks * 3 + mt], b, acc[mt][nt], 0, 0, 0);
        }
    // s1 = relu(acc) overwrites y1 tile (y1 safe in aC2)
    #pragma unroll
    for (int mt = 0; mt < 3; ++mt)
        #pragma unroll
        for (int j = 0; j < 4; ++j) {
            int row = mt * 16 + l4 * 4 + j;
            int sw  = (row & 7) << 4;
            #pragma unroll
            for (int nt = 0; nt < 4; ++nt) {
                int col = nt * 16 + l15;
                *(short*)(syB + row * 128 + ((col * 2) ^ sw)) =
                    (short)hcvt(fmaxf(acc[mt][nt][j], 0.f));
            }
        }

    // ============ GEMM2 pass R2: y1 @ rw1T ============
    #pragma unroll
    for (int mt = 0; mt < 3; ++mt)
        #pragma unroll
        for (int nt = 0; nt < 4; ++nt) acc[mt][nt] = (f32x4)0.f;
    #pragma unroll
    for (int ks = 0; ks < 2; ++ks)
        #pragma unroll
        for (int nt = 0; nt < 4; ++nt) {
            bf16x8 b = gld(FR_W2 + ks * 8 + 4 + nt);
            #pragma unroll
            for (int mt = 0; mt < 3; ++mt)
                acc[mt][nt] = __builtin_amdgcn_mfma_f32_16x16x32_bf16(aC2[ks * 3 + mt], b, acc[mt][nt], 0, 0, 0);
        }

    // ============ tconv1 += acc ============
    #pragma unroll
    for (int dt = 0; dt < 3; ++dt) {
        #pragma unroll
        for (int ks = 0; ks < 2; ++ks) {
            bf16x8 a[3];
            #pragma unroll
            for (int mt = 0; mt < 3; ++mt) {
                int ts    = tA[mt] + dt - 1;
                bool ok   = (ts >= 0) && (ts < 12);
                int srow  = ok ? (mt * 16 + l15 + dt - 1) : (mt * 16 + l15);
                int kb    = (ks * 32 + l4 * 8) * 2;
                bf16x8 av = *(const bf16x8*)(syB + srow * 128 + (kb ^ ((srow & 7) << 4)));
                a[mt] = ok ? av : (bf16x8)(short)0;
            }
            #pragma unroll
            for (int nt = 0; nt < 4; ++nt) {
                bf16x8 b = gld(FR_TW1 + dt * 8 + ks * 4 + nt);
                #pragma unroll
                for (int mt = 0; mt < 3; ++mt)
                    acc[mt][nt] = __builtin_amdgcn_mfma_f32_16x16x32_bf16(a[mt], b, acc[mt][nt], 0, 0, 0);
            }
        }
    }

    // ============ bias + relu + LN1 -> y2 back into tile (DPP) ============
    {
        float bv[4], lgv[4], lbv[4];
        #pragma unroll
        for (int nt = 0; nt < 4; ++nt) {
            int col = nt * 16 + l15;
            bv[nt]  = rb1[col] + tb1[col];
            lgv[nt] = lg1[col];
            lbv[nt] = lb1[col];
        }
        #pragma unroll
        for (int mt = 0; mt < 3; ++mt)
            #pragma unroll
            for (int j = 0; j < 4; ++j) {
                float v[4], sm = 0.f, sq = 0.f;
                #pragma unroll
                for (int nt = 0; nt < 4; ++nt) {
                    v[nt] = fmaxf(acc[mt][nt][j] + bv[nt], 0.f);
                    sm += v[nt]; sq += v[nt] * v[nt];
                }
                sm = red16(sm);
                sq = red16(sq);
                float mu = sm * 0.015625f;
                float is = rsqrtf(sq * 0.015625f - mu * mu + 1e-5f);
                int row = mt * 16 + l4 * 4 + j;
                int sw  = (row & 7) << 4;
                #pragma unroll
                for (int nt = 0; nt < 4; ++nt) {
                    int col = nt * 16 + l15;
                    *(short*)(syB + row * 128 + ((col * 2) ^ sw)) =
                        (short)hcvt((v[nt] - mu) * is * lgv[nt] + lbv[nt]);
                }
            }
    }

    // ============ final: A-row = pair (rows >=4 clamped) ============
    // out[p][po] = fb[po] + sum_{k=(t,f)} y2[p][t][f] * FW[k][po]
    {
        f32x4 acc0 = (f32x4)0.f, acc1 = (f32x4)0.f;
        int p   = (l15 < 4) ? l15 : 0;
        #pragma unroll
        for (int ks = 0; ks < 24; ks += 2) {
            {   // even ks
                int t = ks >> 1, f0 = l4 * 8;
                int row = p * 12 + t;
                bf16x8 a = *(const bf16x8*)(syB + row * 128 + ((f0 * 2) ^ ((row & 7) << 4)));
                acc0 = __builtin_amdgcn_mfma_f32_16x16x32_bf16(a, gld(FR_FW + ks), acc0, 0, 0, 0);
            }
            {   // odd ks
                int t = ks >> 1, f0 = 32 + l4 * 8;
                int row = p * 12 + t;
                bf16x8 a = *(const bf16x8*)(syB + row * 128 + ((f0 * 2) ^ ((row & 7) << 4)));
                acc1 = __builtin_amdgcn_mfma_f32_16x16x32_bf16(a, gld(FR_FW + ks + 1), acc1, 0, 0, 0);
            }
        }
        if (l4 == 0 && l15 < 12) {
            float fbv = fb[l15];
            #pragma unroll
            for (int j = 0; j < 4; ++j)
                out[(long)(pair0 + j) * 12 + l15] = acc0[j] + acc1[j] + fbv;
        }
    }
}

extern "C" void kernel_launch(void* const* d_in, const int* in_sizes, int n_in,
                              void* d_out, int out_size, void* d_ws, size_t ws_size,
                              hipStream_t stream)
{
    (void)in_sizes; (void)n_in; (void)out_size; (void)ws_size;
    const float* x   = (const float*)d_in[0];
    const float* th0 = (const float*)d_in[1];
    const float* tw0 = (const float*)d_in[2];
    const float* tb0 = (const float*)d_in[3];
    const float* rw0 = (const float*)d_in[4];
    const float* rb0 = (const float*)d_in[5];
    const float* lg0 = (const float*)d_in[6];
    const float* lb0 = (const float*)d_in[7];
    const float* th1 = (const float*)d_in[8];
    const float* tw1 = (const float*)d_in[9];
    const float* tb1 = (const float*)d_in[10];
    const float* rw1 = (const float*)d_in[11];
    const float* rb1 = (const float*)d_in[12];
    const float* lg1 = (const float*)d_in[13];
    const float* lb1 = (const float*)d_in[14];
    const float* fw  = (const float*)d_in[15];
    const float* fb  = (const float*)d_in[16];
    float* out = (float*)d_out;
    short* wsb = (short*)d_ws;

    prep<<<240, 256, 0, stream>>>(th0, tw0, rw0, th1, tw1, rw1, fw, wsb);
    mstgcn_mfma<<<4096, 64, 0, stream>>>(x, wsb, tb0, rb0, lg0, lb0,
                                         tb1, rb1, lg1, lb1, fb, out);
}